// Round 17
// baseline (511.909 us; speedup 1.0000x reference)
//
#include <hip/hip_runtime.h>
#include <math.h>

#define BB 4
#define SS 2048
#define NH 8
#define HD 64
#define HID 512
#define EPSV 1e-5f

#define NROWS (BB * SS)                // 8192 (b,s) rows
#define QKV_ELEMS (BB * NH * SS * HD)  // 4,194,304
#define TOTROWS (BB * NH * SS)         // 65536 (b,h,s) rows
#define NJT 16                         // msnap granularity: 128-wide jtiles

typedef __attribute__((ext_vector_type(8))) short short8;
typedef __attribute__((ext_vector_type(4))) float f32x4;

__device__ __forceinline__ unsigned short f2h(float f) {
  _Float16 h = (_Float16)f;
  return __builtin_bit_cast(unsigned short, h);
}
__device__ __forceinline__ float h2f(unsigned short u) {
  return (float)__builtin_bit_cast(_Float16, u);
}

// SAD of 2 packed u16 with accumulate: acc += |a.h0-b.h0| + |a.h1-b.h1|.
// Q/K are u16 fixed-point: u = round((x+8)*4096); offsets cancel in the
// subtraction so acc = 4096 * sum|q-k| exactly.
__device__ __forceinline__ void sad2(unsigned qa, unsigned kb, unsigned& acc) {
  asm("v_sad_u16 %0, %1, %2, %0" : "+v"(acc) : "v"(qa), "v"(kb));
}

__device__ __forceinline__ unsigned pk_mul_f16(unsigned a, unsigned b) {
  unsigned r;
  asm("v_pk_mul_f16 %0, %1, %2" : "=v"(r) : "v"(a), "v"(b));
  return r;
}

// ---------------------------------------------------------------------------
// Merged QKV projection: one launch, blockIdx.z in {0:Q, 1:K, 2:V}.
// C = A(8192 x 512) @ W(512 x 512)^T + bias, 128x128 tile, 256 threads.
// z<2 : u16 fixed-point split-head [bh][s][d] (for SAD scores).
// z==2: f16 transposed per head [bh][d][s] (V -> PV B-operand).
// ---------------------------------------------------------------------------
__global__ __launch_bounds__(256, 2) void qkv_proj_kernel(
    const float* __restrict__ query, const float* __restrict__ key,
    const float* __restrict__ value, const float* __restrict__ Wq,
    const float* __restrict__ Wk, const float* __restrict__ Wv,
    const float* __restrict__ bq, const float* __restrict__ bk,
    const float* __restrict__ bv, unsigned short* __restrict__ Qh,
    unsigned short* __restrict__ Kh, unsigned short* __restrict__ Vt) {
  __shared__ unsigned short As[128][40];  // 32 k + 8 pad
  __shared__ unsigned short Ws[128][40];
  const int z = blockIdx.z;
  const float* A = (z == 0) ? query : (z == 1) ? key : value;
  const float* W = (z == 0) ? Wq : (z == 1) ? Wk : Wv;
  const float* bias = (z == 0) ? bq : (z == 1) ? bk : bv;
  unsigned short* Cout = (z == 0) ? Qh : (z == 1) ? Kh : Vt;

  const int m0 = blockIdx.y * 128;
  const int n0 = blockIdx.x * 128;
  const int tid = threadIdx.x;
  const int lane = tid & 63;
  const int w = tid >> 6;
  const int wr = w >> 1;
  const int wc = w & 1;
  const int l16 = lane & 15;
  const int lq = lane >> 4;

  f32x4 acc[4][4];
#pragma unroll
  for (int mr = 0; mr < 4; ++mr)
#pragma unroll
    for (int nc = 0; nc < 4; ++nc) acc[mr][nc] = (f32x4)0.f;

  for (int k0 = 0; k0 < HID; k0 += 32) {
    __syncthreads();
#pragma unroll
    for (int p = 0; p < 4; ++p) {
      int idx = tid + p * 256;
      int row = idx >> 3;
      int c4 = (idx & 7) * 4;
      float4 av = *(const float4*)&A[(size_t)(m0 + row) * HID + k0 + c4];
      float4 wv = *(const float4*)&W[(size_t)(n0 + row) * HID + k0 + c4];
      ushort4 ab = {f2h(av.x), f2h(av.y), f2h(av.z), f2h(av.w)};
      ushort4 wb = {f2h(wv.x), f2h(wv.y), f2h(wv.z), f2h(wv.w)};
      *(ushort4*)&As[row][c4] = ab;
      *(ushort4*)&Ws[row][c4] = wb;
    }
    __syncthreads();
    const int kb = lq * 8;
    short8 a[4], b[4];
#pragma unroll
    for (int mr = 0; mr < 4; ++mr)
      a[mr] = *(const short8*)&As[wr * 64 + mr * 16 + l16][kb];
#pragma unroll
    for (int nc = 0; nc < 4; ++nc)
      b[nc] = *(const short8*)&Ws[wc * 64 + nc * 16 + l16][kb];
#pragma unroll
    for (int mr = 0; mr < 4; ++mr)
#pragma unroll
      for (int nc = 0; nc < 4; ++nc)
        acc[mr][nc] = __builtin_amdgcn_mfma_f32_16x16x32_f16(a[mr], b[nc], acc[mr][nc], 0, 0, 0);
  }

#pragma unroll
  for (int nc = 0; nc < 4; ++nc) {
    const int n = n0 + wc * 64 + nc * 16 + l16;
    const float bv_ = bias[n];
#pragma unroll
    for (int mr = 0; mr < 4; ++mr) {
#pragma unroll
      for (int jj = 0; jj < 4; ++jj) {
        const int m = m0 + wr * 64 + mr * 16 + lq * 4 + jj;
        float v = acc[mr][nc][jj] + bv_;
        const int b_ = m >> 11, s = m & (SS - 1);
        const int h = n >> 6, d = n & 63;
        if (z == 2) {  // f16 [bh][d][s]
          Cout[(((size_t)(b_ * NH + h)) * HD + d) * SS + s] = f2h(v);
        } else {  // u16 fixed-point [bh][s][d]
          int u = (int)floorf(fmaf(v, 4096.f, 32768.5f));
          u = u < 0 ? 0 : (u > 65535 ? 65535 : u);
          Cout[(((size_t)(b_ * NH + h)) * SS + s) * HD + d] = (unsigned short)u;
        }
      }
    }
  }
}

// ---------------------------------------------------------------------------
// Output projection GEMM: C f32 [m][n] = A_f16(M x 512) @ W(512 x 512)^T + b.
// ---------------------------------------------------------------------------
__global__ __launch_bounds__(256, 2) void gemm_out(const unsigned short* __restrict__ A,
                                                   const float* __restrict__ W,
                                                   const float* __restrict__ bias,
                                                   float* __restrict__ Cout) {
  __shared__ unsigned short As[128][40];
  __shared__ unsigned short Ws[128][40];
  const int m0 = blockIdx.y * 128;
  const int n0 = blockIdx.x * 128;
  const int tid = threadIdx.x;
  const int lane = tid & 63;
  const int w = tid >> 6;
  const int wr = w >> 1;
  const int wc = w & 1;
  const int l16 = lane & 15;
  const int lq = lane >> 4;

  f32x4 acc[4][4];
#pragma unroll
  for (int mr = 0; mr < 4; ++mr)
#pragma unroll
    for (int nc = 0; nc < 4; ++nc) acc[mr][nc] = (f32x4)0.f;

  for (int k0 = 0; k0 < HID; k0 += 32) {
    __syncthreads();
#pragma unroll
    for (int p = 0; p < 2; ++p) {
      int idx = tid + p * 256;
      int row = idx >> 2;
      int ch = (idx & 3) * 8;
      *(uint4*)&As[row][ch] = *(const uint4*)&A[(size_t)(m0 + row) * HID + k0 + ch];
    }
#pragma unroll
    for (int p = 0; p < 4; ++p) {
      int idx = tid + p * 256;
      int row = idx >> 3;
      int c4 = (idx & 7) * 4;
      float4 wv = *(const float4*)&W[(size_t)(n0 + row) * HID + k0 + c4];
      ushort4 wb = {f2h(wv.x), f2h(wv.y), f2h(wv.z), f2h(wv.w)};
      *(ushort4*)&Ws[row][c4] = wb;
    }
    __syncthreads();
    const int kb = lq * 8;
    short8 a[4], b[4];
#pragma unroll
    for (int mr = 0; mr < 4; ++mr)
      a[mr] = *(const short8*)&As[wr * 64 + mr * 16 + l16][kb];
#pragma unroll
    for (int nc = 0; nc < 4; ++nc)
      b[nc] = *(const short8*)&Ws[wc * 64 + nc * 16 + l16][kb];
#pragma unroll
    for (int mr = 0; mr < 4; ++mr)
#pragma unroll
      for (int nc = 0; nc < 4; ++nc)
        acc[mr][nc] = __builtin_amdgcn_mfma_f32_16x16x32_f16(a[mr], b[nc], acc[mr][nc], 0, 0, 0);
  }

#pragma unroll
  for (int nc = 0; nc < 4; ++nc) {
    const int n = n0 + wc * 64 + nc * 16 + l16;
    const float bv = bias[n];
#pragma unroll
    for (int mr = 0; mr < 4; ++mr)
#pragma unroll
      for (int jj = 0; jj < 4; ++jj) {
        const int m = m0 + wr * 64 + mr * 16 + lq * 4 + jj;
        Cout[(size_t)m * HID + n] = acc[mr][nc][jj] + bv;
      }
  }
}

// ---------------------------------------------------------------------------
// FUSED attention, 64-row i-tiles (grid 1024 = 4 blocks/CU for phase
// overlap): phase 1 scores (SAD + online softmax, p' f16 to 2nd half of
// attn rows), phase 2 pv+norm (p32 in-place expansion + PV MFMA).
// stats/msnap in LDS. Same-block p' ordering guaranteed by barriers.
// ---------------------------------------------------------------------------
__global__ __launch_bounds__(512, 4) void attn_fused_kernel(
    const unsigned short* __restrict__ Qh, const unsigned short* __restrict__ Kh,
    const unsigned short* __restrict__ Vt, const int* __restrict__ mask,
    const float* __restrict__ temp, float* __restrict__ attn,
    unsigned short* __restrict__ attn_out) {
  __shared__ unsigned short KP[128][72];  // Ks (128 rows) ph1; Ps (64) ph2
  __shared__ unsigned short Vts[64][72];
  __shared__ float msnap_s[NJT][64];
  __shared__ float mfin_s[64];
  __shared__ float inv_s[64];
  __shared__ float corr_s[64];
  __shared__ int Ms[128];

  const int bh = blockIdx.y;
  const int b = bh >> 3;
  const int h = bh & 7;
  const int i0 = blockIdx.x * 64;
  const int tid = threadIdx.x;
  const float tscale = temp[h] * (1.0f / 4096.0f);  // dist = sad * 2^-12

  const unsigned short* Qb = Qh + (size_t)bh * SS * HD;
  const unsigned short* Kb = Kh + (size_t)bh * SS * HD;
  const unsigned short* Vtb = Vt + (size_t)bh * HD * SS;
  float* attn_b = attn + (size_t)bh * SS * SS;

  // ========================= PHASE 1: scores =========================
  {
    const int trow = tid >> 4;  // 0..31 -> local rows trow, trow+32
    const int cg = tid & 15;    // 0..15 -> cols cg+16c, c=0..7
    const int r0 = i0 + trow;
    const int r1 = r0 + 32;

    float m0 = -INFINITY, m1 = -INFINITY, sg0 = 0.f, sg1 = 0.f;

    for (int j0 = 0; j0 < SS; j0 += 128) {
      __syncthreads();  // protect Ks reads from previous iteration
#pragma unroll
      for (int p = 0; p < 2; ++p) {
        int idx = tid + p * 512;
        int row = idx >> 3;
        int ch = (idx & 7) * 8;
        *(uint4*)&KP[row][ch] = *(const uint4*)&Kb[(size_t)(j0 + row) * HD + ch];
      }
      if (tid < 128) Ms[tid] = mask[b * SS + j0 + tid];
      __syncthreads();

      unsigned d0[8], d1[8];
#pragma unroll
      for (int c = 0; c < 8; ++c) {
        d0[c] = 0u;
        d1[c] = 0u;
      }

// q loaded per-k8 (8 VGPR live, static); unroll 2 bounds load batching.
#pragma unroll 2
      for (int k8 = 0; k8 < 8; ++k8) {
        const uint4 qa = *(const uint4*)&Qb[(size_t)r0 * HD + k8 * 8];
        const uint4 qb = *(const uint4*)&Qb[(size_t)r1 * HD + k8 * 8];
#pragma unroll
        for (int c = 0; c < 8; ++c) {
          const uint4 kx = *(const uint4*)&KP[cg + 16 * c][k8 * 8];
          sad2(qa.x, kx.x, d0[c]);
          sad2(qa.y, kx.y, d0[c]);
          sad2(qa.z, kx.z, d0[c]);
          sad2(qa.w, kx.w, d0[c]);
          sad2(qb.x, kx.x, d1[c]);
          sad2(qb.y, kx.y, d1[c]);
          sad2(qb.z, kx.z, d1[c]);
          sad2(qb.w, kx.w, d1[c]);
        }
      }

      int msk[8];
#pragma unroll
      for (int c = 0; c < 8; ++c) msk[c] = Ms[cg + 16 * c];

      const int jt = j0 >> 7;
      // ---- row 0 ----
      {
        float s[8];
        float rmax = -INFINITY;
#pragma unroll
        for (int c = 0; c < 8; ++c) {
          float sc = -(float)d0[c] * tscale;
          if (msk[c] == 0) sc = -1e9f;
          s[c] = sc;
          rmax = fmaxf(rmax, sc);
        }
#pragma unroll
        for (int off = 1; off < 16; off <<= 1)
          rmax = fmaxf(rmax, __shfl_xor(rmax, off));
        const float mnew = fmaxf(m0, rmax);
        unsigned short* arow = (unsigned short*)(attn_b + (size_t)r0 * SS);
        float psum = 0.f;
#pragma unroll
        for (int c = 0; c < 8; ++c) {
          float pv = __expf(s[c] - mnew);
          psum += pv;
          arow[2048 + j0 + cg + 16 * c] = f2h(pv);  // p' f16, 2nd half
        }
        sg0 = sg0 * __expf(m0 - mnew) + psum;
        m0 = mnew;
        if (cg == 0) msnap_s[jt][trow] = mnew;
      }
      // ---- row 1 ----
      {
        float s[8];
        float rmax = -INFINITY;
#pragma unroll
        for (int c = 0; c < 8; ++c) {
          float sc = -(float)d1[c] * tscale;
          if (msk[c] == 0) sc = -1e9f;
          s[c] = sc;
          rmax = fmaxf(rmax, sc);
        }
#pragma unroll
        for (int off = 1; off < 16; off <<= 1)
          rmax = fmaxf(rmax, __shfl_xor(rmax, off));
        const float mnew = fmaxf(m1, rmax);
        unsigned short* arow = (unsigned short*)(attn_b + (size_t)r1 * SS);
        float psum = 0.f;
#pragma unroll
        for (int c = 0; c < 8; ++c) {
          float pv = __expf(s[c] - mnew);
          psum += pv;
          arow[2048 + j0 + cg + 16 * c] = f2h(pv);
        }
        sg1 = sg1 * __expf(m1 - mnew) + psum;
        m1 = mnew;
        if (cg == 0) msnap_s[jt][trow + 32] = mnew;
      }
    }

    {
      float ssum = sg0;
#pragma unroll
      for (int off = 1; off < 16; off <<= 1) ssum += __shfl_xor(ssum, off);
      if (cg == 0) {
        mfin_s[trow] = m0;
        inv_s[trow] = 1.0f / ssum;
      }
    }
    {
      float ssum = sg1;
#pragma unroll
      for (int off = 1; off < 16; off <<= 1) ssum += __shfl_xor(ssum, off);
      if (cg == 0) {
        mfin_s[trow + 32] = m1;
        inv_s[trow + 32] = 1.0f / ssum;
      }
    }
  }

  __syncthreads();  // stats/msnap ready; p' global writes drained

  // ========================= PHASE 2: pv + norm =========================
  {
    const int lane = tid & 63;
    const int w = tid >> 6;  // 0..7
    const int wr = w >> 1;   // 0..3 -> rows wr*16
    const int wc = w & 1;    // d-half
    const int l16 = lane & 15;
    const int lq = lane >> 4;

    f32x4 acc[2];
#pragma unroll
    for (int nc = 0; nc < 2; ++nc) acc[nc] = (f32x4)0.f;

    const int row = tid >> 3;       // 0..63
    const int ch = (tid & 7) * 8;   // 0..56

    for (int j0 = 0; j0 < SS; j0 += 64) {
      __syncthreads();  // protect prev-iter Ps/Vts reads (and ph1 KP)
      if (tid < 64)
        corr_s[tid] = __expf(msnap_s[j0 >> 7][tid] - mfin_s[tid]) * inv_s[tid];
      // stage Vt tile (512 uint4, 1/thread) + p' load (512 uint4, 1/thread)
      *(uint4*)&Vts[row][ch] = *(const uint4*)&Vtb[(size_t)row * SS + j0 + ch];
      uint4 pv = *(const uint4*)((const unsigned short*)(attn_b +
                                                         (size_t)(i0 + row) * SS) +
                                 2048 + j0 + ch);
      __syncthreads();  // corr_s ready; p' loads drained before f32 stores
      {
        const float cr = corr_s[row];
        unsigned short cu = f2h(cr);
        unsigned c2 = (unsigned)cu | ((unsigned)cu << 16);
        uint4 r;
        r.x = pk_mul_f16(pv.x, c2);
        r.y = pk_mul_f16(pv.y, c2);
        r.z = pk_mul_f16(pv.z, c2);
        r.w = pk_mul_f16(pv.w, c2);
        *(uint4*)&KP[row][ch] = r;
        float* orow = attn_b + (size_t)(i0 + row) * SS + j0 + ch;
        float4 o0 = {h2f((unsigned short)(pv.x)) * cr,
                     h2f((unsigned short)(pv.x >> 16)) * cr,
                     h2f((unsigned short)(pv.y)) * cr,
                     h2f((unsigned short)(pv.y >> 16)) * cr};
        float4 o1 = {h2f((unsigned short)(pv.z)) * cr,
                     h2f((unsigned short)(pv.z >> 16)) * cr,
                     h2f((unsigned short)(pv.w)) * cr,
                     h2f((unsigned short)(pv.w >> 16)) * cr};
        *(float4*)&orow[0] = o0;
        *(float4*)&orow[4] = o1;
      }
      __syncthreads();
// MFMA: out(64x64) += P(64x64) @ V(64x64); wave w: rows wr*16, d-half wc
#pragma unroll
      for (int ks = 0; ks < 2; ++ks) {
        const int kb = ks * 32 + lq * 8;
        short8 a = *(const short8*)&KP[wr * 16 + l16][kb];
        short8 bf[2];
#pragma unroll
        for (int nc = 0; nc < 2; ++nc)
          bf[nc] = *(const short8*)&Vts[wc * 32 + nc * 16 + l16][kb];
#pragma unroll
        for (int nc = 0; nc < 2; ++nc)
          acc[nc] = __builtin_amdgcn_mfma_f32_16x16x32_f16(a, bf[nc], acc[nc], 0, 0, 0);
      }
    }

// epilogue: f16 write [b, s, h*64 + d]
#pragma unroll
    for (int nc = 0; nc < 2; ++nc)
#pragma unroll
      for (int jj = 0; jj < 4; ++jj) {
        const int i = i0 + wr * 16 + lq * 4 + jj;
        const int d = wc * 32 + nc * 16 + l16;
        attn_out[((size_t)(b * SS + i)) * HID + h * HD + d] = f2h(acc[nc][jj]);
      }
  }
}

// ---------------------------------------------------------------------------
// Residual + LayerNorm
// ---------------------------------------------------------------------------
__global__ __launch_bounds__(256) void ln_kernel(const float* __restrict__ proj,
                                                 const float* __restrict__ query,
                                                 const float* __restrict__ gamma,
                                                 const float* __restrict__ beta,
                                                 float* __restrict__ out) {
  const int row = blockIdx.x;
  const int tid = threadIdx.x;

  float x[2];
  float sum = 0.f, sumsq = 0.f;
#pragma unroll
  for (int t = 0; t < 2; ++t) {
    const int c = tid + t * 256;
    float v = proj[(size_t)row * HID + c] + query[(size_t)row * HID + c];
    x[t] = v;
    sum += v;
    sumsq += v * v;
  }
#pragma unroll
  for (int off = 1; off < 64; off <<= 1) {
    sum += __shfl_xor(sum, off);
    sumsq += __shfl_xor(sumsq, off);
  }
  __shared__ float s1[4], s2[4];
  if ((tid & 63) == 0) {
    s1[tid >> 6] = sum;
    s2[tid >> 6] = sumsq;
  }
  __syncthreads();
  sum = s1[0] + s1[1] + s1[2] + s1[3];
  sumsq = s2[0] + s2[1] + s2[2] + s2[3];
  const float mu = sum * (1.f / HID);
  const float var = sumsq * (1.f / HID) - mu * mu;
  const float rstd = rsqrtf(var + EPSV);
#pragma unroll
  for (int t = 0; t < 2; ++t) {
    const int c = tid + t * 256;
    out[(size_t)row * HID + c] = (x[t] - mu) * rstd * gamma[c] + beta[c];
  }
}

// ---------------------------------------------------------------------------
extern "C" void kernel_launch(void* const* d_in, const int* in_sizes, int n_in,
                              void* d_out, int out_size, void* d_ws, size_t ws_size,
                              hipStream_t stream) {
  const float* query = (const float*)d_in[0];
  const float* key = (const float*)d_in[1];
  const float* value = (const float*)d_in[2];
  const int* mask = (const int*)d_in[3];
  const float* Wq = (const float*)d_in[4];
  const float* bq = (const float*)d_in[5];
  const float* Wk = (const float*)d_in[6];
  const float* bk = (const float*)d_in[7];
  const float* Wv = (const float*)d_in[8];
  const float* bv = (const float*)d_in[9];
  const float* Wo = (const float*)d_in[10];
  const float* bo = (const float*)d_in[11];
  const float* temp = (const float*)d_in[12];
  const float* gamma = (const float*)d_in[13];
  const float* beta = (const float*)d_in[14];

  float* out_final = (float*)d_out;                     // (B,S,HID)
  float* attn = (float*)d_out + (size_t)BB * SS * HID;  // (B,H,S,S)

  // workspace layout (32 MB used)
  unsigned short* Qh = (unsigned short*)d_ws;    // u16fx [bh][s][d]  8MB
  unsigned short* Kh = Qh + QKV_ELEMS;           // u16fx [bh][s][d]  8MB
  unsigned short* Vt = Kh + QKV_ELEMS;           // f16 [bh][d][s]    8MB
  unsigned short* aout = Vt + QKV_ELEMS;         // f16 [b*s][512]    8MB
  float* proj = (float*)d_ws;                    // f32, aliases Qh+Kh (16MB)

  const dim3 blk(256);

  // merged Q/K/V projections: one launch, 768 blocks
  qkv_proj_kernel<<<dim3(HID / 128, NROWS / 128, 3), blk, 0, stream>>>(
      query, key, value, Wq, Wk, Wv, bq, bk, bv, Qh, Kh, Vt);

  // fused scores + pv + norm: one launch, 1024 blocks (4/CU)
  attn_fused_kernel<<<dim3(SS / 64, BB * NH), dim3(512), 0, stream>>>(
      Qh, Kh, Vt, mask, temp, attn, aout);

  gemm_out<<<dim3(HID / 128, NROWS / 128), blk, 0, stream>>>(aout, Wo, bo, proj);
  ln_kernel<<<NROWS, blk, 0, stream>>>(proj, query, gamma, beta, out_final);
}

// Round 18
// 483.615 us; speedup vs baseline: 1.0585x; 1.0585x over previous
//
#include <hip/hip_runtime.h>
#include <math.h>

#define BB 4
#define SS 2048
#define NH 8
#define HD 64
#define HID 512
#define EPSV 1e-5f

#define NROWS (BB * SS)                // 8192 (b,s) rows
#define QKV_ELEMS (BB * NH * SS * HD)  // 4,194,304
#define TOTROWS (BB * NH * SS)         // 65536 (b,h,s) rows
#define NJT 16                         // msnap granularity: 128-wide jtiles

typedef __attribute__((ext_vector_type(8))) short short8;
typedef __attribute__((ext_vector_type(4))) float f32x4;

__device__ __forceinline__ unsigned short f2h(float f) {
  _Float16 h = (_Float16)f;
  return __builtin_bit_cast(unsigned short, h);
}
__device__ __forceinline__ float h2f(unsigned short u) {
  return (float)__builtin_bit_cast(_Float16, u);
}

// SAD of 2 packed u16 with accumulate: acc += |a.h0-b.h0| + |a.h1-b.h1|.
// Q/K are u16 fixed-point: u = round((x+8)*4096); offsets cancel in the
// subtraction so acc = 4096 * sum|q-k| exactly.
__device__ __forceinline__ void sad2(unsigned qa, unsigned kb, unsigned& acc) {
  asm("v_sad_u16 %0, %1, %2, %0" : "+v"(acc) : "v"(qa), "v"(kb));
}

__device__ __forceinline__ unsigned pk_mul_f16(unsigned a, unsigned b) {
  unsigned r;
  asm("v_pk_mul_f16 %0, %1, %2" : "=v"(r) : "v"(a), "v"(b));
  return r;
}

// ---------------------------------------------------------------------------
// Merged QKV projection: one launch, blockIdx.z in {0:Q, 1:K, 2:V}.
// C = A(8192 x 512) @ W(512 x 512)^T + bias, 128x128 tile, 256 threads.
// z<2 : u16 fixed-point split-head [bh][s][d] (for SAD scores).
// z==2: f16 transposed per head [bh][d][s] (V -> PV B-operand).
// ---------------------------------------------------------------------------
__global__ __launch_bounds__(256, 2) void qkv_proj_kernel(
    const float* __restrict__ query, const float* __restrict__ key,
    const float* __restrict__ value, const float* __restrict__ Wq,
    const float* __restrict__ Wk, const float* __restrict__ Wv,
    const float* __restrict__ bq, const float* __restrict__ bk,
    const float* __restrict__ bv, unsigned short* __restrict__ Qh,
    unsigned short* __restrict__ Kh, unsigned short* __restrict__ Vt) {
  __shared__ unsigned short As[128][40];  // 32 k + 8 pad
  __shared__ unsigned short Ws[128][40];
  const int z = blockIdx.z;
  const float* A = (z == 0) ? query : (z == 1) ? key : value;
  const float* W = (z == 0) ? Wq : (z == 1) ? Wk : Wv;
  const float* bias = (z == 0) ? bq : (z == 1) ? bk : bv;
  unsigned short* Cout = (z == 0) ? Qh : (z == 1) ? Kh : Vt;

  const int m0 = blockIdx.y * 128;
  const int n0 = blockIdx.x * 128;
  const int tid = threadIdx.x;
  const int lane = tid & 63;
  const int w = tid >> 6;
  const int wr = w >> 1;
  const int wc = w & 1;
  const int l16 = lane & 15;
  const int lq = lane >> 4;

  f32x4 acc[4][4];
#pragma unroll
  for (int mr = 0; mr < 4; ++mr)
#pragma unroll
    for (int nc = 0; nc < 4; ++nc) acc[mr][nc] = (f32x4)0.f;

  for (int k0 = 0; k0 < HID; k0 += 32) {
    __syncthreads();
#pragma unroll
    for (int p = 0; p < 4; ++p) {
      int idx = tid + p * 256;
      int row = idx >> 3;
      int c4 = (idx & 7) * 4;
      float4 av = *(const float4*)&A[(size_t)(m0 + row) * HID + k0 + c4];
      float4 wv = *(const float4*)&W[(size_t)(n0 + row) * HID + k0 + c4];
      ushort4 ab = {f2h(av.x), f2h(av.y), f2h(av.z), f2h(av.w)};
      ushort4 wb = {f2h(wv.x), f2h(wv.y), f2h(wv.z), f2h(wv.w)};
      *(ushort4*)&As[row][c4] = ab;
      *(ushort4*)&Ws[row][c4] = wb;
    }
    __syncthreads();
    const int kb = lq * 8;
    short8 a[4], b[4];
#pragma unroll
    for (int mr = 0; mr < 4; ++mr)
      a[mr] = *(const short8*)&As[wr * 64 + mr * 16 + l16][kb];
#pragma unroll
    for (int nc = 0; nc < 4; ++nc)
      b[nc] = *(const short8*)&Ws[wc * 64 + nc * 16 + l16][kb];
#pragma unroll
    for (int mr = 0; mr < 4; ++mr)
#pragma unroll
      for (int nc = 0; nc < 4; ++nc)
        acc[mr][nc] = __builtin_amdgcn_mfma_f32_16x16x32_f16(a[mr], b[nc], acc[mr][nc], 0, 0, 0);
  }

#pragma unroll
  for (int nc = 0; nc < 4; ++nc) {
    const int n = n0 + wc * 64 + nc * 16 + l16;
    const float bv_ = bias[n];
#pragma unroll
    for (int mr = 0; mr < 4; ++mr) {
#pragma unroll
      for (int jj = 0; jj < 4; ++jj) {
        const int m = m0 + wr * 64 + mr * 16 + lq * 4 + jj;
        float v = acc[mr][nc][jj] + bv_;
        const int b_ = m >> 11, s = m & (SS - 1);
        const int h = n >> 6, d = n & 63;
        if (z == 2) {  // f16 [bh][d][s]
          Cout[(((size_t)(b_ * NH + h)) * HD + d) * SS + s] = f2h(v);
        } else {  // u16 fixed-point [bh][s][d]
          int u = (int)floorf(fmaf(v, 4096.f, 32768.5f));
          u = u < 0 ? 0 : (u > 65535 ? 65535 : u);
          Cout[(((size_t)(b_ * NH + h)) * SS + s) * HD + d] = (unsigned short)u;
        }
      }
    }
  }
}

// ---------------------------------------------------------------------------
// Output projection GEMM: C f32 [m][n] = A_f16(M x 512) @ W(512 x 512)^T + b.
// ---------------------------------------------------------------------------
__global__ __launch_bounds__(256, 2) void gemm_out(const unsigned short* __restrict__ A,
                                                   const float* __restrict__ W,
                                                   const float* __restrict__ bias,
                                                   float* __restrict__ Cout) {
  __shared__ unsigned short As[128][40];
  __shared__ unsigned short Ws[128][40];
  const int m0 = blockIdx.y * 128;
  const int n0 = blockIdx.x * 128;
  const int tid = threadIdx.x;
  const int lane = tid & 63;
  const int w = tid >> 6;
  const int wr = w >> 1;
  const int wc = w & 1;
  const int l16 = lane & 15;
  const int lq = lane >> 4;

  f32x4 acc[4][4];
#pragma unroll
  for (int mr = 0; mr < 4; ++mr)
#pragma unroll
    for (int nc = 0; nc < 4; ++nc) acc[mr][nc] = (f32x4)0.f;

  for (int k0 = 0; k0 < HID; k0 += 32) {
    __syncthreads();
#pragma unroll
    for (int p = 0; p < 2; ++p) {
      int idx = tid + p * 256;
      int row = idx >> 2;
      int ch = (idx & 3) * 8;
      *(uint4*)&As[row][ch] = *(const uint4*)&A[(size_t)(m0 + row) * HID + k0 + ch];
    }
#pragma unroll
    for (int p = 0; p < 4; ++p) {
      int idx = tid + p * 256;
      int row = idx >> 3;
      int c4 = (idx & 7) * 4;
      float4 wv = *(const float4*)&W[(size_t)(n0 + row) * HID + k0 + c4];
      ushort4 wb = {f2h(wv.x), f2h(wv.y), f2h(wv.z), f2h(wv.w)};
      *(ushort4*)&Ws[row][c4] = wb;
    }
    __syncthreads();
    const int kb = lq * 8;
    short8 a[4], b[4];
#pragma unroll
    for (int mr = 0; mr < 4; ++mr)
      a[mr] = *(const short8*)&As[wr * 64 + mr * 16 + l16][kb];
#pragma unroll
    for (int nc = 0; nc < 4; ++nc)
      b[nc] = *(const short8*)&Ws[wc * 64 + nc * 16 + l16][kb];
#pragma unroll
    for (int mr = 0; mr < 4; ++mr)
#pragma unroll
      for (int nc = 0; nc < 4; ++nc)
        acc[mr][nc] = __builtin_amdgcn_mfma_f32_16x16x32_f16(a[mr], b[nc], acc[mr][nc], 0, 0, 0);
  }

#pragma unroll
  for (int nc = 0; nc < 4; ++nc) {
    const int n = n0 + wc * 64 + nc * 16 + l16;
    const float bv = bias[n];
#pragma unroll
    for (int mr = 0; mr < 4; ++mr)
#pragma unroll
      for (int jj = 0; jj < 4; ++jj) {
        const int m = m0 + wr * 64 + mr * 16 + lq * 4 + jj;
        Cout[(size_t)m * HID + n] = acc[mr][nc][jj] + bv;
      }
  }
}

// ---------------------------------------------------------------------------
// FUSED attention: scores (SAD + online softmax, p' f16 to 2nd half of attn
// rows) THEN pv+norm (p32 in-place expansion + PV MFMA) for the same
// (bh, 128-row i-tile). stats/msnap live in LDS only. Safety: pv reads only
// this block's p' (written in phase 1, drained by barrier); f32 writes only
// this block's rows.
// ---------------------------------------------------------------------------
__global__ __launch_bounds__(512, 4) void attn_fused_kernel(
    const unsigned short* __restrict__ Qh, const unsigned short* __restrict__ Kh,
    const unsigned short* __restrict__ Vt, const int* __restrict__ mask,
    const float* __restrict__ temp, float* __restrict__ attn,
    unsigned short* __restrict__ attn_out) {
  __shared__ unsigned short KP[128][72];   // Ks in phase 1, Ps in phase 2
  __shared__ unsigned short Vts[64][72];
  __shared__ float msnap_s[NJT][128];
  __shared__ float mfin_s[128];
  __shared__ float inv_s[128];
  __shared__ float corr_s[128];
  __shared__ int Ms[128];

  const int bh = blockIdx.y;
  const int b = bh >> 3;
  const int h = bh & 7;
  const int i0 = blockIdx.x * 128;
  const int tid = threadIdx.x;
  const float tscale = temp[h] * (1.0f / 4096.0f);  // dist = sad * 2^-12

  const unsigned short* Qb = Qh + (size_t)bh * SS * HD;
  const unsigned short* Kb = Kh + (size_t)bh * SS * HD;
  const unsigned short* Vtb = Vt + (size_t)bh * HD * SS;
  float* attn_b = attn + (size_t)bh * SS * SS;

  // ========================= PHASE 1: scores =========================
  {
    const int trow = tid >> 4;  // 0..31
    const int cg = tid & 15;    // 0..15

    float m[4], sg[4];
#pragma unroll
    for (int rr = 0; rr < 4; ++rr) {
      m[rr] = -INFINITY;
      sg[rr] = 0.f;
    }

    for (int j0 = 0; j0 < SS; j0 += 128) {
      __syncthreads();  // protect Ks reads from previous iteration
#pragma unroll
      for (int p = 0; p < 2; ++p) {
        int idx = tid + p * 512;
        int row = idx >> 3;
        int ch = (idx & 7) * 8;
        *(uint4*)&KP[row][ch] = *(const uint4*)&Kb[(size_t)(j0 + row) * HD + ch];
      }
      if (tid < 128) Ms[tid] = mask[b * SS + j0 + tid];
      __syncthreads();

      unsigned d[4][8];
#pragma unroll
      for (int rr = 0; rr < 4; ++rr)
#pragma unroll
        for (int c = 0; c < 8; ++c) d[rr][c] = 0u;

#pragma unroll 2
      for (int k8 = 0; k8 < 8; ++k8) {
        uint4 q4[4];
#pragma unroll
        for (int rr = 0; rr < 4; ++rr)
          q4[rr] = *(const uint4*)&Qb[(size_t)(i0 + trow + 32 * rr) * HD + k8 * 8];
#pragma unroll
        for (int c = 0; c < 8; ++c) {
          const uint4 kx = *(const uint4*)&KP[cg + 16 * c][k8 * 8];
#pragma unroll
          for (int rr = 0; rr < 4; ++rr) {
            sad2(q4[rr].x, kx.x, d[rr][c]);
            sad2(q4[rr].y, kx.y, d[rr][c]);
            sad2(q4[rr].z, kx.z, d[rr][c]);
            sad2(q4[rr].w, kx.w, d[rr][c]);
          }
        }
      }

      int msk[8];
#pragma unroll
      for (int c = 0; c < 8; ++c) msk[c] = Ms[cg + 16 * c];

      const int jt = j0 >> 7;
#pragma unroll
      for (int rr = 0; rr < 4; ++rr) {
        float s[8];
        float rmax = -INFINITY;
#pragma unroll
        for (int c = 0; c < 8; ++c) {
          float sc = -(float)d[rr][c] * tscale;
          if (msk[c] == 0) sc = -1e9f;
          s[c] = sc;
          rmax = fmaxf(rmax, sc);
        }
#pragma unroll
        for (int off = 1; off < 16; off <<= 1)
          rmax = fmaxf(rmax, __shfl_xor(rmax, off));
        const float mnew = fmaxf(m[rr], rmax);
        const int i = i0 + trow + 32 * rr;
        unsigned short* arow = (unsigned short*)(attn_b + (size_t)i * SS);
        float psum = 0.f;
#pragma unroll
        for (int c = 0; c < 8; ++c) {
          float pv = __expf(s[c] - mnew);
          psum += pv;
          arow[2048 + j0 + cg + 16 * c] = f2h(pv);  // p' f16, 2nd half of row
        }
        sg[rr] = sg[rr] * __expf(m[rr] - mnew) + psum;
        m[rr] = mnew;
        if (cg == 0) msnap_s[jt][trow + 32 * rr] = mnew;
      }
    }

#pragma unroll
    for (int rr = 0; rr < 4; ++rr) {
      float ssum = sg[rr];
#pragma unroll
      for (int off = 1; off < 16; off <<= 1) ssum += __shfl_xor(ssum, off);
      if (cg == 0) {
        mfin_s[trow + 32 * rr] = m[rr];
        inv_s[trow + 32 * rr] = 1.0f / ssum;
      }
    }
  }

  __syncthreads();  // stats/msnap ready; p' global writes drained

  // ========================= PHASE 2: pv + norm =========================
  {
    const int lane = tid & 63;
    const int w = tid >> 6;  // 0..7
    const int wr = w >> 1;   // row-group
    const int wc = w & 1;    // d-half
    const int l16 = lane & 15;
    const int lq = lane >> 4;

    f32x4 acc[2][2];
#pragma unroll
    for (int mr = 0; mr < 2; ++mr)
#pragma unroll
      for (int nc = 0; nc < 2; ++nc) acc[mr][nc] = (f32x4)0.f;

    for (int j0 = 0; j0 < SS; j0 += 64) {
      __syncthreads();  // protect prev-iter Ps/Vts reads (and phase-1 KP)
      if (tid < 128)
        corr_s[tid] = __expf(msnap_s[j0 >> 7][tid] - mfin_s[tid]) * inv_s[tid];
      // stage Vt tile (512 uint4, 1/thread) + p' loads (1024 uint4, 2/thread)
      {
        int row = tid >> 3;
        int ch = (tid & 7) * 8;
        *(uint4*)&Vts[row][ch] = *(const uint4*)&Vtb[(size_t)row * SS + j0 + ch];
      }
      uint4 pv[2];
#pragma unroll
      for (int p = 0; p < 2; ++p) {
        int idx = tid + p * 512;
        int row = idx >> 3;  // 0..127
        int ch = (idx & 7) * 8;
        pv[p] = *(const uint4*)((const unsigned short*)(attn_b +
                                                        (size_t)(i0 + row) * SS) +
                                2048 + j0 + ch);
      }
      __syncthreads();  // corr_s ready; p' loads drained before f32 stores
#pragma unroll
      for (int p = 0; p < 2; ++p) {
        int idx = tid + p * 512;
        int row = idx >> 3;
        int ch = (idx & 7) * 8;
        const float cr = corr_s[row];
        unsigned short cu = f2h(cr);
        unsigned c2 = (unsigned)cu | ((unsigned)cu << 16);
        uint4 r;
        r.x = pk_mul_f16(pv[p].x, c2);
        r.y = pk_mul_f16(pv[p].y, c2);
        r.z = pk_mul_f16(pv[p].z, c2);
        r.w = pk_mul_f16(pv[p].w, c2);
        *(uint4*)&KP[row][ch] = r;
        float* orow = attn_b + (size_t)(i0 + row) * SS + j0 + ch;
        float4 o0 = {h2f((unsigned short)(pv[p].x)) * cr,
                     h2f((unsigned short)(pv[p].x >> 16)) * cr,
                     h2f((unsigned short)(pv[p].y)) * cr,
                     h2f((unsigned short)(pv[p].y >> 16)) * cr};
        float4 o1 = {h2f((unsigned short)(pv[p].z)) * cr,
                     h2f((unsigned short)(pv[p].z >> 16)) * cr,
                     h2f((unsigned short)(pv[p].w)) * cr,
                     h2f((unsigned short)(pv[p].w >> 16)) * cr};
        *(float4*)&orow[0] = o0;
        *(float4*)&orow[4] = o1;
      }
      __syncthreads();
// MFMA: out(128x64) += P(128x64) @ V(64x64); wave w: rows wr*32+, d-half wc
#pragma unroll
      for (int ks = 0; ks < 2; ++ks) {
        const int kb = ks * 32 + lq * 8;
        short8 a[2], bf[2];
#pragma unroll
        for (int mr = 0; mr < 2; ++mr)
          a[mr] = *(const short8*)&KP[wr * 32 + mr * 16 + l16][kb];
#pragma unroll
        for (int nc = 0; nc < 2; ++nc)
          bf[nc] = *(const short8*)&Vts[wc * 32 + nc * 16 + l16][kb];
#pragma unroll
        for (int mr = 0; mr < 2; ++mr)
#pragma unroll
          for (int nc = 0; nc < 2; ++nc)
            acc[mr][nc] =
                __builtin_amdgcn_mfma_f32_16x16x32_f16(a[mr], bf[nc], acc[mr][nc], 0, 0, 0);
      }
    }

// epilogue: f16 write [b, s, h*64 + d]
#pragma unroll
    for (int mr = 0; mr < 2; ++mr)
#pragma unroll
      for (int nc = 0; nc < 2; ++nc)
#pragma unroll
        for (int jj = 0; jj < 4; ++jj) {
          const int i = i0 + wr * 32 + mr * 16 + lq * 4 + jj;
          const int d = wc * 32 + nc * 16 + l16;
          attn_out[((size_t)(b * SS + i)) * HID + h * HD + d] = f2h(acc[mr][nc][jj]);
        }
  }
}

// ---------------------------------------------------------------------------
// Residual + LayerNorm
// ---------------------------------------------------------------------------
__global__ __launch_bounds__(256) void ln_kernel(const float* __restrict__ proj,
                                                 const float* __restrict__ query,
                                                 const float* __restrict__ gamma,
                                                 const float* __restrict__ beta,
                                                 float* __restrict__ out) {
  const int row = blockIdx.x;
  const int tid = threadIdx.x;

  float x[2];
  float sum = 0.f, sumsq = 0.f;
#pragma unroll
  for (int t = 0; t < 2; ++t) {
    const int c = tid + t * 256;
    float v = proj[(size_t)row * HID + c] + query[(size_t)row * HID + c];
    x[t] = v;
    sum += v;
    sumsq += v * v;
  }
#pragma unroll
  for (int off = 1; off < 64; off <<= 1) {
    sum += __shfl_xor(sum, off);
    sumsq += __shfl_xor(sumsq, off);
  }
  __shared__ float s1[4], s2[4];
  if ((tid & 63) == 0) {
    s1[tid >> 6] = sum;
    s2[tid >> 6] = sumsq;
  }
  __syncthreads();
  sum = s1[0] + s1[1] + s1[2] + s1[3];
  sumsq = s2[0] + s2[1] + s2[2] + s2[3];
  const float mu = sum * (1.f / HID);
  const float var = sumsq * (1.f / HID) - mu * mu;
  const float rstd = rsqrtf(var + EPSV);
#pragma unroll
  for (int t = 0; t < 2; ++t) {
    const int c = tid + t * 256;
    out[(size_t)row * HID + c] = (x[t] - mu) * rstd * gamma[c] + beta[c];
  }
}

// ---------------------------------------------------------------------------
extern "C" void kernel_launch(void* const* d_in, const int* in_sizes, int n_in,
                              void* d_out, int out_size, void* d_ws, size_t ws_size,
                              hipStream_t stream) {
  const float* query = (const float*)d_in[0];
  const float* key = (const float*)d_in[1];
  const float* value = (const float*)d_in[2];
  const int* mask = (const int*)d_in[3];
  const float* Wq = (const float*)d_in[4];
  const float* bq = (const float*)d_in[5];
  const float* Wk = (const float*)d_in[6];
  const float* bk = (const float*)d_in[7];
  const float* Wv = (const float*)d_in[8];
  const float* bv = (const float*)d_in[9];
  const float* Wo = (const float*)d_in[10];
  const float* bo = (const float*)d_in[11];
  const float* temp = (const float*)d_in[12];
  const float* gamma = (const float*)d_in[13];
  const float* beta = (const float*)d_in[14];

  float* out_final = (float*)d_out;                     // (B,S,HID)
  float* attn = (float*)d_out + (size_t)BB * SS * HID;  // (B,H,S,S)

  // workspace layout (32 MB used)
  unsigned short* Qh = (unsigned short*)d_ws;    // u16fx [bh][s][d]  8MB
  unsigned short* Kh = Qh + QKV_ELEMS;           // u16fx [bh][s][d]  8MB
  unsigned short* Vt = Kh + QKV_ELEMS;           // f16 [bh][d][s]    8MB
  unsigned short* aout = Vt + QKV_ELEMS;         // f16 [b*s][512]    8MB
  float* proj = (float*)d_ws;                    // f32, aliases Qh+Kh (16MB)

  const dim3 blk(256);

  // merged Q/K/V projections: one launch, 768 blocks
  qkv_proj_kernel<<<dim3(HID / 128, NROWS / 128, 3), blk, 0, stream>>>(
      query, key, value, Wq, Wk, Wv, bq, bk, bv, Qh, Kh, Vt);

  // fused scores + pv + norm: one launch, 512 blocks
  attn_fused_kernel<<<dim3(SS / 128, BB * NH), dim3(512), 0, stream>>>(
      Qh, Kh, Vt, mask, temp, attn, aout);

  gemm_out<<<dim3(HID / 128, NROWS / 128), blk, 0, stream>>>(aout, Wo, bo, proj);
  ln_kernel<<<NROWS, blk, 0, stream>>>(proj, query, gamma, beta, out_final);
}